// Round 13
// baseline (148.078 us; speedup 1.0000x reference)
//
#include <hip/hip_runtime.h>

// R20 = R19 with the asm operand-type fix: uint4 is a STRUCT (indirect
// register input -> compile error); asm operands must be ext_vector_type.
// mfma16_acc now union-casts a/b to v4u before the asm. No other change.
// R19 intent: unblock R15's dual-ii ILP (session-best 128.1us total despite
// 18MB spills) by moving PV accumulators + vb to AGPRs ("+a" asm MFMA),
// k1f/v1f non-persistent, R18 XCD-pinned maps everywhere.
// Tripwires: WRITE_SIZE ~768KB (no spill), VGPR_Count <= 128.

#define B_ 2
#define N_ 192
#define DIM_ 512
#define H_ 8
#define DH_ 64
#define EPS_RMS 1.1920929e-7f
#define QSC 0.18033688011112042f   // 0.125 * log2(e)  (logits in base-2)

typedef float v4f __attribute__((ext_vector_type(4)));
typedef short v8s __attribute__((ext_vector_type(8)));
typedef unsigned int v4u __attribute__((ext_vector_type(4)));

// ---------- helpers ----------
__device__ __forceinline__ unsigned int cvtpk(float a, float b) {
  unsigned int d;
  asm("v_cvt_pk_bf16_f32 %0, %1, %2" : "=v"(d) : "v"(a), "v"(b));
  return d;
}
__device__ __forceinline__ float bf16_lo(unsigned int u) { return __uint_as_float(u << 16); }
__device__ __forceinline__ float bf16_hi(unsigned int u) { return __uint_as_float(u & 0xffff0000u); }

#if __has_builtin(__builtin_amdgcn_exp2f)
__device__ __forceinline__ float fexp2(float x) { return __builtin_amdgcn_exp2f(x); }
#else
__device__ __forceinline__ float fexp2(float x) {
  float r; asm("v_exp_f32 %0, %1\n\ts_nop 1" : "=v"(r) : "v"(x)); return r;
}
#endif

__device__ __forceinline__ v4f mfma16(uint4 a, uint4 b, v4f c) {
  union { uint4 u; v8s s; } ua, ub;
  ua.u = a; ub.u = b;
  return __builtin_amdgcn_mfma_f32_16x16x32_bf16(ua.s, ub.s, c, 0, 0, 0);
}

// PV accumulate: C/D pinned to AGPR, B from AGPR, A from VGPR.
// asm operands MUST be ext_vector_type (uint4 struct = "indirect" -> error).
__device__ __forceinline__ void mfma16_acc(uint4 a, uint4 b, v4f& c) {
  union { uint4 u; v4u v; } ua, ub;
  ua.u = a; ub.u = b;
  asm("v_mfma_f32_16x16x32_bf16 %0, %1, %2, %0"
      : "+a"(c) : "v"(ua.v), "a"(ub.v));
}

__device__ __forceinline__ void split8(const float* s, uint4& hi, uint4& lo) {
  float4 f0 = *(const float4*)s;
  float4 f1 = *(const float4*)(s + 4);
  hi.x = cvtpk(f0.x, f0.y); hi.y = cvtpk(f0.z, f0.w);
  hi.z = cvtpk(f1.x, f1.y); hi.w = cvtpk(f1.z, f1.w);
  lo.x = cvtpk(f0.x - bf16_lo(hi.x), f0.y - bf16_hi(hi.x));
  lo.y = cvtpk(f0.z - bf16_lo(hi.y), f0.w - bf16_hi(hi.y));
  lo.z = cvtpk(f1.x - bf16_lo(hi.z), f1.y - bf16_hi(hi.z));
  lo.w = cvtpk(f1.z - bf16_lo(hi.w), f1.w - bf16_hi(hi.w));
}

// ---------- Kernel 0: prepack (unchanged, R18) ----------
__global__ __launch_bounds__(256)
void prepack_kernel(const float* __restrict__ tokens, const float* __restrict__ w_qkv,
                    const float* __restrict__ w_out,
                    uint4* __restrict__ AtkHi, uint4* __restrict__ AtkLo,
                    uint4* __restrict__ WqHi,  uint4* __restrict__ WqLo,
                    uint4* __restrict__ WoHi,  uint4* __restrict__ WoLo)
{
  int idx = blockIdx.x * 256 + threadIdx.x;     // < 221184
  const float* src; uint4 *dh, *dl; int o;
  if (idx < 24576) {
    int token = idx >> 6, kc = (idx >> 3) & 7, g = idx & 7;
    src = tokens + (size_t)token*DIM_ + kc*64 + g*8;
    o = (((token >> 5)*8 + kc)*8 + g)*32 + (token & 31);
    dh = AtkHi; dl = AtkLo;
  } else if (idx < 188416) {
    int t = idx - 24576;
    int row = t >> 6, kc = (t >> 3) & 7, g = t & 7;
    src = w_qkv + (size_t)row*DIM_ + kc*64 + g*8;
    o = (((row >> 6)*8 + kc)*8 + g)*64 + (row & 63);
    dh = WqHi; dl = WqLo;
  } else {
    int t = idx - 188416;
    int row = t >> 6, kc = (t >> 3) & 7, g = t & 7;
    src = w_out + (size_t)row*DIM_ + kc*64 + g*8;
    o = (((row >> 6)*8 + kc)*8 + g)*64 + (row & 63);
    dh = WoHi; dl = WoLo;
  }
  uint4 hi, lo; split8(src, hi, lo);
  dh[o] = hi; dl[o] = lo;
}

// ---------- Kernel 1: QKV GEMM + RMSNorm (unchanged, R18 XCD-pinned) ----------
__global__ __launch_bounds__(256)
void qkv_mfma_kernel(const uint4* __restrict__ AtkHi, const uint4* __restrict__ AtkLo,
                     const uint4* __restrict__ WqHi,  const uint4* __restrict__ WqLo,
                     const float* __restrict__ qw, const float* __restrict__ k1w,
                     const float* __restrict__ k2w, const float* __restrict__ v1w,
                     const float* __restrict__ v2w,
                     float* __restrict__ Q,
                     uint4* __restrict__ K1P, uint2* __restrict__ V1P,
                     uint4* __restrict__ K2P, uint4* __restrict__ V2P)
{
  const int bid = blockIdx.x;            // 0..479
  const int xcd = bid & 7;
  const int jj  = bid >> 3;              // 0..59
  const int bn  = xcd * 5 + (jj % 5);    // 0..39
  const int bm  = jj / 5;                // 0..11
  const int tid = threadIdx.x;
  const int w = tid >> 6, l = tid & 63;
  const int c = l & 15, q = l >> 4;
  const int mhalf = w & 1, nhalf = w >> 1;

  __shared__ float tile[32*64];
  __shared__ float red[32][2];

  v4f acc[2] = {(v4f){0,0,0,0}, (v4f){0,0,0,0}};

  for (int kc = 0; kc < 8; ++kc) {
    #pragma unroll
    for (int kh = 0; kh < 2; ++kh) {
      int g = kh*4 + q;
      int aidx = ((bm*8 + kc)*8 + g)*32 + mhalf*16 + c;
      uint4 ah = AtkHi[aidx];
      uint4 al = AtkLo[aidx];
      #pragma unroll
      for (int nt = 0; nt < 2; ++nt) {
        int bidx = ((bn*8 + kc)*8 + g)*64 + nhalf*32 + nt*16 + c;
        uint4 bh = WqHi[bidx];
        uint4 bl = WqLo[bidx];
        acc[nt] = mfma16(ah, bh, acc[nt]);
        acc[nt] = mfma16(ah, bl, acc[nt]);
        acc[nt] = mfma16(al, bh, acc[nt]);
      }
    }
  }

  float ss[4];
  #pragma unroll
  for (int r = 0; r < 4; ++r) {
    ss[r] = acc[0][r]*acc[0][r] + acc[1][r]*acc[1][r];
    #pragma unroll
    for (int off = 1; off < 16; off <<= 1) ss[r] += __shfl_xor(ss[r], off, 64);
  }
  if (c == 0) {
    #pragma unroll
    for (int r = 0; r < 4; ++r) red[mhalf*16 + q*4 + r][nhalf] = ss[r];
  }
  __syncthreads();

  const float* nw; int hh; int kind;
  if (bn < 8)       { nw = qw; hh = bn; kind = 0; }
  else if (bn < 24) { int g = bn - 8;  hh = g >> 1; kind = (g & 1) ? 2 : 1; nw = (g & 1) ? k2w : k1w; }
  else              { int g = bn - 24; hh = g >> 1; kind = (g & 1) ? 4 : 3; nw = (g & 1) ? v2w : v1w; }

  const int b = (bm >= 6) ? 1 : 0;
  const int bmm = bm - b*6;
  const int bh = b*8 + hh;

  float sc[4];
  #pragma unroll
  for (int r = 0; r < 4; ++r) {
    int row = mhalf*16 + q*4 + r;
    sc[r] = rsqrtf((red[row][0] + red[row][1]) * (1.0f/64.0f) + EPS_RMS);
  }

  if (kind == 0) {
    #pragma unroll
    for (int r = 0; r < 4; ++r) {
      int row = mhalf*16 + q*4 + r;
      size_t obase = (((size_t)bh)*N_ + bmm*32 + row)*DH_;
      #pragma unroll
      for (int nt = 0; nt < 2; ++nt) {
        int d = nhalf*32 + nt*16 + c;
        Q[obase + d] = acc[nt][r] * sc[r] * nw[d];
      }
    }
    return;
  }

  #pragma unroll
  for (int r = 0; r < 4; ++r) {
    int row = mhalf*16 + q*4 + r;
    #pragma unroll
    for (int nt = 0; nt < 2; ++nt) {
      int d = nhalf*32 + nt*16 + c;
      tile[row*64 + d] = acc[nt][r] * sc[r] * nw[d];
    }
  }
  __syncthreads();

  if (kind == 1) {
    int jt_l = tid >> 7, ks = (tid >> 6) & 1, ll = tid & 63;
    int qq = ll >> 4, cc = ll & 15;
    const float* sp = tile + (jt_l*16 + cc)*64 + ks*32 + qq*8;
    uint4 wv;
    wv.x = cvtpk(sp[0], sp[1]); wv.y = cvtpk(sp[2], sp[3]);
    wv.z = cvtpk(sp[4], sp[5]); wv.w = cvtpk(sp[6], sp[7]);
    K1P[((bh*12 + bmm*2 + jt_l)*2 + ks)*64 + ll] = wv;
  } else if (kind == 2) {
    int ntl = tid >> 7, ks2 = (tid >> 6) & 1, ll = tid & 63;
    int tok = ntl*16 + (ll & 15);
    int d0 = ks2*32 + ((ll >> 4) << 3);
    const float* sp = tile + tok*64 + d0;
    uint4 wv;
    wv.x = cvtpk(sp[0], sp[1]); wv.y = cvtpk(sp[2], sp[3]);
    wv.z = cvtpk(sp[4], sp[5]); wv.w = cvtpk(sp[6], sp[7]);
    K2P[(size_t)bh*1536 + ((bmm*2 + ntl)*2 + ks2)*64 + ll] = wv;
  } else if (kind == 3) {
    #pragma unroll
    for (int pass = 0; pass < 2; ++pass) {
      int e = tid + 256*pass;
      int jt_l = e >> 8, dt = (e >> 6) & 3, ll = e & 63;
      int qq = ll >> 4, cc = ll & 15;
      int r0 = jt_l*16 + qq*4;
      int d = dt*16 + cc;
      uint2 wv;
      wv.x = cvtpk(tile[r0*64 + d],       tile[(r0+1)*64 + d]);
      wv.y = cvtpk(tile[(r0+2)*64 + d],   tile[(r0+3)*64 + d]);
      V1P[((bh*12 + bmm*2 + jt_l)*4 + dt)*64 + ll] = wv;
    }
  } else {
    int ntd = tid >> 6, ll = tid & 63;
    int dd = ntd*16 + (ll & 15);
    int t0 = (ll >> 4) << 3;
    uint4 wv;
    wv.x = cvtpk(tile[(t0+0)*64 + dd], tile[(t0+1)*64 + dd]);
    wv.y = cvtpk(tile[(t0+2)*64 + dd], tile[(t0+3)*64 + dd]);
    wv.z = cvtpk(tile[(t0+4)*64 + dd], tile[(t0+5)*64 + dd]);
    wv.w = cvtpk(tile[(t0+6)*64 + dd], tile[(t0+7)*64 + dd]);
    V2P[(size_t)bh*1536 + (ntd*6 + bmm)*64 + ll] = wv;
  }
}

// ---------- Kernel 2: two-simplicial attention, dual-ii + AGPR accumulators ----------
// grid 512, XCD-pinned: bh = (bid&7) + 8*((bid>>3)&1), sub = bid>>4.
// Per wave TWO independent chains (A=ii, B=ii+1) share kb/vb. PV accumulates
// in AGPRs (asm mfma "+a"); S-MFMAs stay builtin (compiler handles the
// MFMA->exp2 hazard). k1f reloaded per pair (not persistent).
__global__ __launch_bounds__(256, 2)
void attn_kernel(const float* __restrict__ Qg,
                 const uint4* __restrict__ K1Pg, const uint2* __restrict__ V1Pg,
                 const uint4* __restrict__ K2P,  const uint4* __restrict__ V2P,
                 unsigned short* __restrict__ ATThi, unsigned short* __restrict__ ATTlo)
{
  __shared__ __align__(16) unsigned char lds[57344];
  // K2B [0,24576) | V2B [24576,49152) | P: 4 waves x {PwA 1KB, PwB 1KB}
  uint4* K2B  = (uint4*)(lds);
  uint4* V2B  = (uint4*)(lds + 24576);

  const int tid = threadIdx.x;
  const int w = tid >> 6, l = tid & 63;
  const int c = l & 15, q = l >> 4;
  const int bid = blockIdx.x;
  const int bh = (bid & 7) + 8 * ((bid >> 3) & 1);   // XCD-pinned head map
  const int sub = bid >> 4;                           // 0..31
  const int b = bh >> 3, h = bh & 7;
  const int i0 = sub * 6;
  const size_t base = (size_t)bh * (N_ * DH_);

  {
    const uint4* s2 = K2P + (size_t)bh*1536;
    const uint4* s3 = V2P + (size_t)bh*1536;
    #pragma unroll
    for (int t = 0; t < 6; ++t) K2B[tid + 256*t] = s2[tid + 256*t];
    #pragma unroll
    for (int t = 0; t < 6; ++t) V2B[tid + 256*t] = s3[tid + 256*t];
  }

  __syncthreads();

  unsigned char* PwA = lds + 49152 + w*2048;
  unsigned char* PwB = PwA + 1024;
  const int rbase = (((q >> 1) * 64 + (q & 1) * 32 + c)) << 3;

  for (int ip = 0; ip < 3; ++ip) {
    // q rows for the pair
    float qvA[2][8], qvB[2][8];
    #pragma unroll
    for (int ks = 0; ks < 2; ++ks) {
      const float* sA = Qg + base + (size_t)(i0 + ip*2 + 0)*64 + ks*32 + (q << 3);
      float4 a0 = *(const float4*)sA;
      float4 a1 = *(const float4*)(sA + 4);
      qvA[ks][0]=a0.x*QSC; qvA[ks][1]=a0.y*QSC; qvA[ks][2]=a0.z*QSC; qvA[ks][3]=a0.w*QSC;
      qvA[ks][4]=a1.x*QSC; qvA[ks][5]=a1.y*QSC; qvA[ks][6]=a1.z*QSC; qvA[ks][7]=a1.w*QSC;
      const float* sB = Qg + base + (size_t)(i0 + ip*2 + 1)*64 + ks*32 + (q << 3);
      float4 b0 = *(const float4*)sB;
      float4 b1 = *(const float4*)(sB + 4);
      qvB[ks][0]=b0.x*QSC; qvB[ks][1]=b0.y*QSC; qvB[ks][2]=b0.z*QSC; qvB[ks][3]=b0.w*QSC;
      qvB[ks][4]=b1.x*QSC; qvB[ks][5]=b1.y*QSC; qvB[ks][6]=b1.z*QSC; qvB[ks][7]=b1.w*QSC;
    }
    // afr for both chains; k1f loaded per (jt,ks), not persistent
    uint4 afrA[3][2], afrB[3][2];
    #pragma unroll
    for (int jt = 0; jt < 3; ++jt)
      #pragma unroll
      for (int ks = 0; ks < 2; ++ks) {
        uint4 kf = K1Pg[((bh*12 + w*3 + jt)*2 + ks)*64 + l];
        afrA[jt][ks].x = cvtpk(bf16_lo(kf.x)*qvA[ks][0], bf16_hi(kf.x)*qvA[ks][1]);
        afrA[jt][ks].y = cvtpk(bf16_lo(kf.y)*qvA[ks][2], bf16_hi(kf.y)*qvA[ks][3]);
        afrA[jt][ks].z = cvtpk(bf16_lo(kf.z)*qvA[ks][4], bf16_hi(kf.z)*qvA[ks][5]);
        afrA[jt][ks].w = cvtpk(bf16_lo(kf.w)*qvA[ks][6], bf16_hi(kf.w)*qvA[ks][7]);
        afrB[jt][ks].x = cvtpk(bf16_lo(kf.x)*qvB[ks][0], bf16_hi(kf.x)*qvB[ks][1]);
        afrB[jt][ks].y = cvtpk(bf16_lo(kf.y)*qvB[ks][2], bf16_hi(kf.y)*qvB[ks][3]);
        afrB[jt][ks].z = cvtpk(bf16_lo(kf.z)*qvB[ks][4], bf16_hi(kf.z)*qvB[ks][5]);
        afrB[jt][ks].w = cvtpk(bf16_lo(kf.w)*qvB[ks][6], bf16_hi(kf.w)*qvB[ks][7]);
      }

    v4f raccA[3][4], raccB[3][4];
    #pragma unroll
    for (int jt = 0; jt < 3; ++jt)
      #pragma unroll
      for (int dt = 0; dt < 4; ++dt) {
        raccA[jt][dt] = (v4f){0.f, 0.f, 0.f, 0.f};
        raccB[jt][dt] = (v4f){0.f, 0.f, 0.f, 0.f};
      }
    float psumA = 0.f, psumB = 0.f;

    for (int ch = 0; ch < 6; ++ch) {
      uint4 kb[2][2];
      #pragma unroll
      for (int mt = 0; mt < 2; ++mt)
        #pragma unroll
        for (int ks = 0; ks < 2; ++ks)
          kb[mt][ks] = K2B[((ch*2 + mt)*2 + ks)*64 + l];
      uint4 vb[4];
      #pragma unroll
      for (int dt = 0; dt < 4; ++dt)
        vb[dt] = V2B[(dt*6 + ch)*64 + l];

      #pragma unroll
      for (int jt = 0; jt < 3; ++jt) {
        // chain A: S phase (builtin MFMA; compiler handles MFMA->exp2 hazard)
        v4f zA0 = (v4f){0.f,0.f,0.f,0.f}, zA1 = (v4f){0.f,0.f,0.f,0.f};
        zA0 = mfma16(kb[0][0], afrA[jt][0], zA0);
        zA1 = mfma16(kb[1][0], afrA[jt][0], zA1);
        zA0 = mfma16(kb[0][1], afrA[jt][1], zA0);
        zA1 = mfma16(kb[1][1], afrA[jt][1], zA1);
        // chain B: S phase
        v4f zB0 = (v4f){0.f,0.f,0.f,0.f}, zB1 = (v4f){0.f,0.f,0.f,0.f};
        zB0 = mfma16(kb[0][0], afrB[jt][0], zB0);
        zB1 = mfma16(kb[1][0], afrB[jt][0], zB1);
        zB0 = mfma16(kb[0][1], afrB[jt][1], zB0);
        zB1 = mfma16(kb[1][1], afrB[jt][1], zB1);
        // exp2 + pack + psum
        float a00 = fexp2(zA0[0]), a01 = fexp2(zA0[1]), a02 = fexp2(zA0[2]), a03 = fexp2(zA0[3]);
        float a10 = fexp2(zA1[0]), a11 = fexp2(zA1[1]), a12 = fexp2(zA1[2]), a13 = fexp2(zA1[3]);
        psumA += (a00 + a01) + (a02 + a03);
        psumA += (a10 + a11) + (a12 + a13);
        float b00 = fexp2(zB0[0]), b01 = fexp2(zB0[1]), b02 = fexp2(zB0[2]), b03 = fexp2(zB0[3]);
        float b10 = fexp2(zB1[0]), b11 = fexp2(zB1[1]), b12 = fexp2(zB1[2]), b13 = fexp2(zB1[3]);
        psumB += (b00 + b01) + (b02 + b03);
        psumB += (b10 + b11) + (b12 + b13);
        uint2 wA0; wA0.x = cvtpk(a00, a01); wA0.y = cvtpk(a02, a03);
        uint2 wA1; wA1.x = cvtpk(a10, a11); wA1.y = cvtpk(a12, a13);
        uint2 wB0; wB0.x = cvtpk(b00, b01); wB0.y = cvtpk(b02, b03);
        uint2 wB1; wB1.x = cvtpk(b10, b11); wB1.y = cvtpk(b12, b13);
        *(uint2*)(PwA + (l << 3)) = wA0;
        *(uint2*)(PwA + ((64 + l) << 3)) = wA1;
        *(uint2*)(PwB + (l << 3)) = wB0;
        *(uint2*)(PwB + ((64 + l) << 3)) = wB1;
        // P reads (same-wave DS ordering)
        uint2 rA0 = *(const uint2*)(PwA + rbase);
        uint2 rA1 = *(const uint2*)(PwA + rbase + 128);
        uint2 rB0 = *(const uint2*)(PwB + rbase);
        uint2 rB1 = *(const uint2*)(PwB + rbase + 128);
        uint4 paA; paA.x = rA0.x; paA.y = rA0.y; paA.z = rA1.x; paA.w = rA1.y;
        uint4 paB; paB.x = rB0.x; paB.y = rB0.y; paB.z = rB1.x; paB.w = rB1.y;
        // PV phase, AGPR accumulate (asm mfma, C/D + B in AGPR)
        #pragma unroll
        for (int dt = 0; dt < 4; ++dt)
          mfma16_acc(paA, vb[dt], raccA[jt][dt]);
        #pragma unroll
        for (int dt = 0; dt < 4; ++dt)
          mfma16_acc(paB, vb[dt], raccB[jt][dt]);
      }
    }

    float lsumA = psumA, lsumB = psumB;
    #pragma unroll
    for (int off = 32; off; off >>= 1) {
      lsumA += __shfl_xor(lsumA, off, 64);
      lsumB += __shfl_xor(lsumB, off, 64);
    }

    // V1 loaded per pair (not persistent)
    float opA[4] = {0.f, 0.f, 0.f, 0.f};
    float opB[4] = {0.f, 0.f, 0.f, 0.f};
    #pragma unroll
    for (int jt = 0; jt < 3; ++jt)
      #pragma unroll
      for (int dt = 0; dt < 4; ++dt) {
        uint2 vf = V1Pg[((bh*12 + w*3 + jt)*4 + dt)*64 + l];
        float v1x = bf16_lo(vf.x), v1y = bf16_hi(vf.x);
        float v1z = bf16_lo(vf.y), v1w2 = bf16_hi(vf.y);
        opA[dt] = fmaf(v1x, raccA[jt][dt][0], opA[dt]);
        opA[dt] = fmaf(v1y, raccA[jt][dt][1], opA[dt]);
        opA[dt] = fmaf(v1z, raccA[jt][dt][2], opA[dt]);
        opA[dt] = fmaf(v1w2, raccA[jt][dt][3], opA[dt]);
        opB[dt] = fmaf(v1x, raccB[jt][dt][0], opB[dt]);
        opB[dt] = fmaf(v1y, raccB[jt][dt][1], opB[dt]);
        opB[dt] = fmaf(v1z, raccB[jt][dt][2], opB[dt]);
        opB[dt] = fmaf(v1w2, raccB[jt][dt][3], opB[dt]);
      }
    #pragma unroll
    for (int dt = 0; dt < 4; ++dt) {
      opA[dt] += __shfl_xor(opA[dt], 16, 64);
      opA[dt] += __shfl_xor(opA[dt], 32, 64);
      opB[dt] += __shfl_xor(opB[dt], 16, 64);
      opB[dt] += __shfl_xor(opB[dt], 32, 64);
    }
    // per-wave partials into own P tiles (P dead): redF [0,256), lsum @256
    if (l < 16) {
      #pragma unroll
      for (int dt = 0; dt < 4; ++dt) {
        *(float*)(PwA + ((dt*16 + l) << 2)) = opA[dt];
        *(float*)(PwB + ((dt*16 + l) << 2)) = opB[dt];
      }
    }
    if (l == 0) {
      *(float*)(PwA + 256) = lsumA;
      *(float*)(PwB + 256) = lsumB;
    }
    __syncthreads();
    if (tid < 128) {
      const int which = tid >> 6, tt = tid & 63;
      float o = 0.f, lt = 0.f;
      #pragma unroll
      for (int ww = 0; ww < 4; ++ww) {
        const unsigned char* pp = lds + 49152 + ww*2048 + which*1024;
        o  += *(const float*)(pp + (tt << 2));
        lt += *(const float*)(pp + 256);
      }
      float v = o / lt;
      int m_tok = b*N_ + i0 + ip*2 + which;
      int mt = m_tok >> 5, mloc = m_tok & 31;
      int g = tt >> 3, e = tt & 7;
      int off = ((((mt*8 + h)*8 + g)*32 + mloc) << 3) + e;
      unsigned short hs = (unsigned short)cvtpk(v, v);
      float resid = v - __uint_as_float(((unsigned int)hs) << 16);
      unsigned short lsb = (unsigned short)cvtpk(resid, resid);
      ATThi[off] = hs; ATTlo[off] = lsb;
    }
    __syncthreads();
  }
}

// ---------- Kernel 3: output projection (unchanged, R18 XCD-pinned) ----------
__global__ __launch_bounds__(256)
void out_proj_kernel(const uint4* __restrict__ AHi, const uint4* __restrict__ ALo,
                     const uint4* __restrict__ WoHi, const uint4* __restrict__ WoLo,
                     float* __restrict__ out)
{
  const int bid = blockIdx.x;                 // 0..191
  const int bn  = (bid & 7) * 2 + ((bid >> 3) & 1);  // 0..15
  const int bm  = bid >> 4;                   // 0..11
  const int tid = threadIdx.x;
  const int w = tid >> 6, l = tid & 63;
  const int c = l & 15, q = l >> 4;
  const int mhalf = w & 1, nhalf = w >> 1;

  v4f acc = (v4f){0,0,0,0};

  for (int kc = 0; kc < 8; ++kc) {
    #pragma unroll
    for (int kh = 0; kh < 2; ++kh) {
      int g = kh*4 + q;
      int aidx = ((bm*8 + kc)*8 + g)*32 + mhalf*16 + c;
      uint4 ah = AHi[aidx];
      uint4 al = ALo[aidx];
      int nrow = bn*32 + nhalf*16 + c;
      int bidx = (((nrow >> 6)*8 + kc)*8 + g)*64 + (nrow & 63);
      uint4 bh = WoHi[bidx];
      uint4 bl = WoLo[bidx];
      acc = mfma16(ah, bh, acc);
      acc = mfma16(ah, bl, acc);
      acc = mfma16(al, bh, acc);
    }
  }

  #pragma unroll
  for (int r = 0; r < 4; ++r) {
    int m = bm*32 + mhalf*16 + q*4 + r;
    int n = bn*32 + nhalf*16 + c;
    out[(size_t)m*DIM_ + n] = acc[r];
  }
}

// ---------- launch ----------
extern "C" void kernel_launch(void* const* d_in, const int* in_sizes, int n_in,
                              void* d_out, int out_size, void* d_ws, size_t ws_size,
                              hipStream_t stream) {
  const float* tokens = (const float*)d_in[0];
  const float* w_qkv  = (const float*)d_in[1];
  const float* w_out  = (const float*)d_in[2];
  const float* qw     = (const float*)d_in[3];
  const float* k1w    = (const float*)d_in[4];
  const float* k2w    = (const float*)d_in[5];
  const float* v1w    = (const float*)d_in[6];
  const float* v2w    = (const float*)d_in[7];
  float* out = (float*)d_out;

  float* ws = (float*)d_ws;
  float* Q    = ws;                                  // 196608
  uint4* K1P  = (uint4*)(ws + 196608);               // 98304 f
  uint2* V1P  = (uint2*)(ws + 196608 + 98304);       // 98304 f
  uint4* K2P  = (uint4*)(ws + 196608 + 2*98304);     // 98304 f
  uint4* V2P  = (uint4*)(ws + 196608 + 3*98304);     // 98304 f
  uint4* AtkHi= (uint4*)(ws + 196608 + 4*98304);     // 98304 f
  uint4* AtkLo= (uint4*)(ws + 196608 + 5*98304);     // 98304 f
  uint4* WqHi = (uint4*)(ws + 196608 + 6*98304);     // 655360 f
  uint4* WqLo = (uint4*)(ws + 196608 + 6*98304 + 655360);
  uint4* WoHi = (uint4*)(ws + 196608 + 6*98304 + 2*655360);          // 131072 f
  uint4* WoLo = (uint4*)(ws + 196608 + 6*98304 + 2*655360 + 131072);
  unsigned short* ATThi = (unsigned short*)AtkHi;
  unsigned short* ATTlo = (unsigned short*)AtkLo;

  prepack_kernel<<<864, 256, 0, stream>>>(tokens, w_qkv, w_out,
                                          AtkHi, AtkLo, WqHi, WqLo, WoHi, WoLo);
  qkv_mfma_kernel<<<480, 256, 0, stream>>>(AtkHi, AtkLo, WqHi, WqLo,
                                           qw, k1w, k2w, v1w, v2w,
                                           Q, K1P, V1P, K2P, V2P);
  attn_kernel<<<512, 256, 0, stream>>>(Q, K1P, V1P, K2P, V2P, ATThi, ATTlo);
  out_proj_kernel<<<192, 256, 0, stream>>>((const uint4*)ATThi, (const uint4*)ATTlo,
                                           WoHi, WoLo, out);
}

// Round 16
// 128.246 us; speedup vs baseline: 1.1546x; 1.1546x over previous
//
#include <hip/hip_runtime.h>

// R23 = byte-exact resubmission of R13 (best clean verified: 129.15us total,
// attn 43.3us, absmax 1.22e-4, no spills). Rationale: fusion arc closed
// (R21 cooperative launch illegal under graph capture; R22 spin-barrier
// killed containers twice -> G16 dispatch-timing hazard confirmed). All
// 13 attn/caching theories landed in the 128-131us plateau band; locking
// in the safest best-known configuration.

#define B_ 2
#define N_ 192
#define DIM_ 512
#define H_ 8
#define DH_ 64
#define EPS_RMS 1.1920929e-7f
#define QSC 0.18033688011112042f   // 0.125 * log2(e)  (logits in base-2)
#define ARR_ (B_*H_*N_*DH_)        // 196608

typedef float v4f __attribute__((ext_vector_type(4)));
typedef short v8s __attribute__((ext_vector_type(8)));

// ---------- helpers ----------
__device__ __forceinline__ unsigned int cvtpk(float a, float b) {
  unsigned int d;
  asm("v_cvt_pk_bf16_f32 %0, %1, %2" : "=v"(d) : "v"(a), "v"(b));
  return d;
}
__device__ __forceinline__ float bf16_lo(unsigned int u) { return __uint_as_float(u << 16); }
__device__ __forceinline__ float bf16_hi(unsigned int u) { return __uint_as_float(u & 0xffff0000u); }

// exp2 via builtin ONLY (R4 lesson: raw inline-asm v_exp_f32 lacks the
// trans-op hazard wait -> stale VGPR -> NaN).
#if __has_builtin(__builtin_amdgcn_exp2f)
__device__ __forceinline__ float fexp2(float x) { return __builtin_amdgcn_exp2f(x); }
#else
__device__ __forceinline__ float fexp2(float x) {
  float r; asm("v_exp_f32 %0, %1\n\ts_nop 1" : "=v"(r) : "v"(x)); return r;
}
#endif

__device__ __forceinline__ v4f mfma16(uint4 a, uint4 b, v4f c) {
  union { uint4 u; v8s s; } ua, ub;
  ua.u = a; ub.u = b;
  return __builtin_amdgcn_mfma_f32_16x16x32_bf16(ua.s, ub.s, c, 0, 0, 0);
}

__device__ __forceinline__ void split8(const float* s, uint4& hi, uint4& lo) {
  float4 f0 = *(const float4*)s;
  float4 f1 = *(const float4*)(s + 4);
  hi.x = cvtpk(f0.x, f0.y); hi.y = cvtpk(f0.z, f0.w);
  hi.z = cvtpk(f1.x, f1.y); hi.w = cvtpk(f1.z, f1.w);
  lo.x = cvtpk(f0.x - bf16_lo(hi.x), f0.y - bf16_hi(hi.x));
  lo.y = cvtpk(f0.z - bf16_lo(hi.y), f0.w - bf16_hi(hi.y));
  lo.z = cvtpk(f1.x - bf16_lo(hi.z), f1.y - bf16_hi(hi.z));
  lo.w = cvtpk(f1.z - bf16_lo(hi.w), f1.w - bf16_hi(hi.w));
}

// ---------- Kernel 0: prepack tokens + w_qkv + w_out -> frag-ordered hi/lo bf16 ----------
__global__ __launch_bounds__(256)
void prepack_kernel(const float* __restrict__ tokens, const float* __restrict__ w_qkv,
                    const float* __restrict__ w_out,
                    uint4* __restrict__ AtkHi, uint4* __restrict__ AtkLo,
                    uint4* __restrict__ WqHi,  uint4* __restrict__ WqLo,
                    uint4* __restrict__ WoHi,  uint4* __restrict__ WoLo)
{
  int idx = blockIdx.x * 256 + threadIdx.x;     // < 221184
  const float* src; uint4 *dh, *dl; int o;
  if (idx < 24576) {
    int token = idx >> 6, kc = (idx >> 3) & 7, g = idx & 7;
    src = tokens + (size_t)token*DIM_ + kc*64 + g*8;
    o = (((token >> 5)*8 + kc)*8 + g)*32 + (token & 31);
    dh = AtkHi; dl = AtkLo;
  } else if (idx < 188416) {
    int t = idx - 24576;
    int row = t >> 6, kc = (t >> 3) & 7, g = t & 7;
    src = w_qkv + (size_t)row*DIM_ + kc*64 + g*8;
    o = (((row >> 6)*8 + kc)*8 + g)*64 + (row & 63);
    dh = WqHi; dl = WqLo;
  } else {
    int t = idx - 188416;
    int row = t >> 6, kc = (t >> 3) & 7, g = t & 7;
    src = w_out + (size_t)row*DIM_ + kc*64 + g*8;
    o = (((row >> 6)*8 + kc)*8 + g)*64 + (row & 63);
    dh = WoHi; dl = WoLo;
  }
  uint4 hi, lo; split8(src, hi, lo);
  dh[o] = hi; dl[o] = lo;
}

// ---------- Kernel 1: QKV GEMM (split-bf16 MFMA, barrier-free K loop) + RMSNorm ----------
__global__ __launch_bounds__(256)
void qkv_mfma_kernel(const uint4* __restrict__ AtkHi, const uint4* __restrict__ AtkLo,
                     const uint4* __restrict__ WqHi,  const uint4* __restrict__ WqLo,
                     const float* __restrict__ qw, const float* __restrict__ k1w,
                     const float* __restrict__ k2w, const float* __restrict__ v1w,
                     const float* __restrict__ v2w,
                     float* __restrict__ Q,
                     uint4* __restrict__ K1P, uint2* __restrict__ V1P,
                     uint4* __restrict__ K2P, uint4* __restrict__ V2P)
{
  const int bn = blockIdx.x;   // 0..39 (64 rows of w_qkv)
  const int bm = blockIdx.y;   // 0..11 (32 tokens)
  const int tid = threadIdx.x;
  const int w = tid >> 6, l = tid & 63;
  const int c = l & 15, q = l >> 4;
  const int mhalf = w & 1, nhalf = w >> 1;

  __shared__ float tile[32*64];     // 8KB, epilogue only
  __shared__ float red[32][2];

  v4f acc[2] = {(v4f){0,0,0,0}, (v4f){0,0,0,0}};

  for (int kc = 0; kc < 8; ++kc) {
    #pragma unroll
    for (int kh = 0; kh < 2; ++kh) {
      int g = kh*4 + q;
      int aidx = ((bm*8 + kc)*8 + g)*32 + mhalf*16 + c;
      uint4 ah = AtkHi[aidx];
      uint4 al = AtkLo[aidx];
      #pragma unroll
      for (int nt = 0; nt < 2; ++nt) {
        int bidx = ((bn*8 + kc)*8 + g)*64 + nhalf*32 + nt*16 + c;
        uint4 bh = WqHi[bidx];
        uint4 bl = WqLo[bidx];
        acc[nt] = mfma16(ah, bh, acc[nt]);
        acc[nt] = mfma16(ah, bl, acc[nt]);
        acc[nt] = mfma16(al, bh, acc[nt]);
      }
    }
  }

  // RMSNorm row sums (D layout: col = nhalf*32+nt*16+c, row = mhalf*16+q*4+r)
  float ss[4];
  #pragma unroll
  for (int r = 0; r < 4; ++r) {
    ss[r] = acc[0][r]*acc[0][r] + acc[1][r]*acc[1][r];
    #pragma unroll
    for (int off = 1; off < 16; off <<= 1) ss[r] += __shfl_xor(ss[r], off, 64);
  }
  if (c == 0) {
    #pragma unroll
    for (int r = 0; r < 4; ++r) red[mhalf*16 + q*4 + r][nhalf] = ss[r];
  }
  __syncthreads();

  // classify destination
  const float* nw; int hh; int kind;   // 0=Q 1=K1 2=K2 3=V1 4=V2
  if (bn < 8)       { nw = qw; hh = bn; kind = 0; }
  else if (bn < 24) { int g = bn - 8;  hh = g >> 1; kind = (g & 1) ? 2 : 1; nw = (g & 1) ? k2w : k1w; }
  else              { int g = bn - 24; hh = g >> 1; kind = (g & 1) ? 4 : 3; nw = (g & 1) ? v2w : v1w; }

  const int b = (bm >= 6) ? 1 : 0;
  const int bmm = bm - b*6;
  const int bh = b*8 + hh;

  float sc[4];
  #pragma unroll
  for (int r = 0; r < 4; ++r) {
    int row = mhalf*16 + q*4 + r;
    sc[r] = rsqrtf((red[row][0] + red[row][1]) * (1.0f/64.0f) + EPS_RMS);
  }

  if (kind == 0) {
    #pragma unroll
    for (int r = 0; r < 4; ++r) {
      int row = mhalf*16 + q*4 + r;
      size_t obase = (((size_t)bh)*N_ + bmm*32 + row)*DH_;
      #pragma unroll
      for (int nt = 0; nt < 2; ++nt) {
        int d = nhalf*32 + nt*16 + c;
        Q[obase + d] = acc[nt][r] * sc[r] * nw[d];
      }
    }
    return;
  }

  // normalized fp32 -> LDS tile [32 tok][64 d]
  #pragma unroll
  for (int r = 0; r < 4; ++r) {
    int row = mhalf*16 + q*4 + r;
    #pragma unroll
    for (int nt = 0; nt < 2; ++nt) {
      int d = nhalf*32 + nt*16 + c;
      tile[row*64 + d] = acc[nt][r] * sc[r] * nw[d];
    }
  }
  __syncthreads();

  if (kind == 1) {
    int jt_l = tid >> 7, ks = (tid >> 6) & 1, ll = tid & 63;
    int qq = ll >> 4, cc = ll & 15;
    const float* sp = tile + (jt_l*16 + cc)*64 + ks*32 + qq*8;
    uint4 wv;
    wv.x = cvtpk(sp[0], sp[1]); wv.y = cvtpk(sp[2], sp[3]);
    wv.z = cvtpk(sp[4], sp[5]); wv.w = cvtpk(sp[6], sp[7]);
    K1P[((bh*12 + bmm*2 + jt_l)*2 + ks)*64 + ll] = wv;
  } else if (kind == 2) {
    int ntl = tid >> 7, ks2 = (tid >> 6) & 1, ll = tid & 63;
    int tok = ntl*16 + (ll & 15);
    int d0 = ks2*32 + ((ll >> 4) << 3);
    const float* sp = tile + tok*64 + d0;
    uint4 wv;
    wv.x = cvtpk(sp[0], sp[1]); wv.y = cvtpk(sp[2], sp[3]);
    wv.z = cvtpk(sp[4], sp[5]); wv.w = cvtpk(sp[6], sp[7]);
    K2P[(size_t)bh*1536 + ((bmm*2 + ntl)*2 + ks2)*64 + ll] = wv;
  } else if (kind == 3) {
    #pragma unroll
    for (int pass = 0; pass < 2; ++pass) {
      int e = tid + 256*pass;
      int jt_l = e >> 8, dt = (e >> 6) & 3, ll = e & 63;
      int qq = ll >> 4, cc = ll & 15;
      int r0 = jt_l*16 + qq*4;
      int d = dt*16 + cc;
      uint2 wv;
      wv.x = cvtpk(tile[r0*64 + d],       tile[(r0+1)*64 + d]);
      wv.y = cvtpk(tile[(r0+2)*64 + d],   tile[(r0+3)*64 + d]);
      V1P[((bh*12 + bmm*2 + jt_l)*4 + dt)*64 + ll] = wv;
    }
  } else {
    int ntd = tid >> 6, ll = tid & 63;
    int dd = ntd*16 + (ll & 15);
    int t0 = (ll >> 4) << 3;
    uint4 wv;
    wv.x = cvtpk(tile[(t0+0)*64 + dd], tile[(t0+1)*64 + dd]);
    wv.y = cvtpk(tile[(t0+2)*64 + dd], tile[(t0+3)*64 + dd]);
    wv.z = cvtpk(tile[(t0+4)*64 + dd], tile[(t0+5)*64 + dd]);
    wv.w = cvtpk(tile[(t0+6)*64 + dd], tile[(t0+7)*64 + dd]);
    V2P[(size_t)bh*1536 + (ntd*6 + bmm)*64 + ll] = wv;
  }
}

// ---------- Kernel 2: two-simplicial attention ----------
// grid 512: bh = bid>>5, i0 = (bid&31)*6. 4 waves, wave w owns j in [48w,48w+48).
// Flattened t = ch*3+jt (18 steps), dual 1KB P buffers per wave (parity t&1),
// depth-1 software pipeline: read P(t-1) early, S(t), write P(t), PV(t-1).
// LDS 57344 B: K2B 24576 | V2B 24576 | P 4 waves x 2KB. redF/lsum alias wave
// P buffer 0 after the t-loop (P dead there).
__global__ __launch_bounds__(256, 2)
void attn_kernel(const float* __restrict__ Qg,
                 const uint4* __restrict__ K1Pg, const uint2* __restrict__ V1Pg,
                 const uint4* __restrict__ K2P,  const uint4* __restrict__ V2P,
                 unsigned short* __restrict__ ATThi, unsigned short* __restrict__ ATTlo)
{
  __shared__ __align__(16) unsigned char lds[57344];
  uint4* K2B  = (uint4*)(lds);
  uint4* V2B  = (uint4*)(lds + 24576);

  const int tid = threadIdx.x;
  const int w = tid >> 6, l = tid & 63;
  const int c = l & 15, q = l >> 4;
  const int bid = blockIdx.x;
  const int bh = bid >> 5;
  const int sub = bid & 31;
  const int b = bh >> 3, h = bh & 7;
  const int i0 = sub * 6;
  const size_t base = (size_t)bh * (N_ * DH_);

  // flat copy of packed K2/V2 into LDS
  {
    const uint4* s2 = K2P + (size_t)bh*1536;
    const uint4* s3 = V2P + (size_t)bh*1536;
    #pragma unroll
    for (int t = 0; t < 6; ++t) K2B[tid + 256*t] = s2[tid + 256*t];
    #pragma unroll
    for (int t = 0; t < 6; ++t) V2B[tid + 256*t] = s3[tid + 256*t];
  }

  // K1 frags (bf16, prepacked): j = w*48+jt*16+c, d = ks*32+q*8+e
  uint4 k1f[6];
  #pragma unroll
  for (int jt = 0; jt < 3; ++jt)
    #pragma unroll
    for (int ks = 0; ks < 2; ++ks)
      k1f[jt*2+ks] = K1Pg[((bh*12 + w*3 + jt)*2 + ks)*64 + l];
  // V1 (bf16, prepacked D-read order)
  uint2 v1f[12];
  #pragma unroll
  for (int jt = 0; jt < 3; ++jt)
    #pragma unroll
    for (int dt = 0; dt < 4; ++dt)
      v1f[jt*4+dt] = V1Pg[((bh*12 + w*3 + jt)*4 + dt)*64 + l];

  __syncthreads();

  unsigned char* Pbase = lds + 49152 + w*2048;   // wave-private, 2 x 1KB
  const int rbase = (((q >> 1) * 64 + (q & 1) * 32 + c)) << 3;

  for (int ii = 0; ii < 6; ++ii) {
    float qv[2][8];
    #pragma unroll
    for (int ks = 0; ks < 2; ++ks) {
      const float* s = Qg + base + (size_t)(i0 + ii)*64 + ks*32 + (q << 3);
      float4 a = *(const float4*)s;
      float4 bq = *(const float4*)(s + 4);
      qv[ks][0]=a.x*QSC;  qv[ks][1]=a.y*QSC;  qv[ks][2]=a.z*QSC;  qv[ks][3]=a.w*QSC;
      qv[ks][4]=bq.x*QSC; qv[ks][5]=bq.y*QSC; qv[ks][6]=bq.z*QSC; qv[ks][7]=bq.w*QSC;
    }
    // B-frags: (K1 .* q_scaled) -> bf16
    uint4 afr[3][2];
    #pragma unroll
    for (int jt = 0; jt < 3; ++jt)
      #pragma unroll
      for (int ks = 0; ks < 2; ++ks) {
        uint4 kf = k1f[jt*2+ks];
        afr[jt][ks].x = cvtpk(bf16_lo(kf.x)*qv[ks][0], bf16_hi(kf.x)*qv[ks][1]);
        afr[jt][ks].y = cvtpk(bf16_lo(kf.y)*qv[ks][2], bf16_hi(kf.y)*qv[ks][3]);
        afr[jt][ks].z = cvtpk(bf16_lo(kf.z)*qv[ks][4], bf16_hi(kf.z)*qv[ks][5]);
        afr[jt][ks].w = cvtpk(bf16_lo(kf.w)*qv[ks][6], bf16_hi(kf.w)*qv[ks][7]);
      }

    v4f racc[3][4];
    #pragma unroll
    for (int jt = 0; jt < 3; ++jt)
      #pragma unroll
      for (int dt = 0; dt < 4; ++dt)
        racc[jt][dt] = (v4f){0.f, 0.f, 0.f, 0.f};
    float psum = 0.f;

    uint4 kbA[2][2];
    uint4 vbA[2][4];   // [ch&1][dt] — ping-pong so PV(t-1) at ch boundary sees old vb

    #pragma unroll
    for (int t = 0; t < 18; ++t) {
      const int ch = t / 3, jt = t % 3, par = ch & 1;
      // (1) issue P(t-1) read early — latency hides under S(t)
      uint2 r0, r1;
      if (t > 0) {
        const unsigned char* Pp = Pbase + (((t - 1) & 1) << 10);
        r0 = *(const uint2*)(Pp + rbase);
        r1 = *(const uint2*)(Pp + rbase + 128);
      }
      // (2) ch-boundary fragment loads
      if (jt == 0) {
        #pragma unroll
        for (int mt = 0; mt < 2; ++mt)
          #pragma unroll
          for (int ks = 0; ks < 2; ++ks)
            kbA[mt][ks] = K2B[((ch*2 + mt)*2 + ks)*64 + l];
        #pragma unroll
        for (int dt = 0; dt < 4; ++dt)
          vbA[par][dt] = V2B[(dt*6 + ch)*64 + l];
      }
      // (3) S phase — mt0/mt1 chains interleaved
      v4f z0 = (v4f){0.f, 0.f, 0.f, 0.f};
      v4f z1 = (v4f){0.f, 0.f, 0.f, 0.f};
      z0 = mfma16(kbA[0][0], afr[jt][0], z0);
      z1 = mfma16(kbA[1][0], afr[jt][0], z1);
      z0 = mfma16(kbA[0][1], afr[jt][1], z0);
      z1 = mfma16(kbA[1][1], afr[jt][1], z1);
      float p00 = fexp2(z0[0]), p01 = fexp2(z0[1]), p02 = fexp2(z0[2]), p03 = fexp2(z0[3]);
      float p10 = fexp2(z1[0]), p11 = fexp2(z1[1]), p12 = fexp2(z1[2]), p13 = fexp2(z1[3]);
      uint2 w0; w0.x = cvtpk(p00, p01); w0.y = cvtpk(p02, p03);
      uint2 w1; w1.x = cvtpk(p10, p11); w1.y = cvtpk(p12, p13);
      unsigned char* Pt = Pbase + ((t & 1) << 10);
      *(uint2*)(Pt + (l << 3)) = w0;          // slot l        (mt=0)
      *(uint2*)(Pt + ((64 + l) << 3)) = w1;   // slot 64+l     (mt=1)
      psum += (p00 + p01) + (p02 + p03);
      psum += (p10 + p11) + (p12 + p13);
      // (4) consume P(t-1)
      if (t > 0) {
        const int pj = (t - 1) % 3, ppar = ((t - 1) / 3) & 1;
        uint4 pa; pa.x = r0.x; pa.y = r0.y; pa.z = r1.x; pa.w = r1.y;
        #pragma unroll
        for (int dt = 0; dt < 4; ++dt)
          racc[pj][dt] = mfma16(pa, vbA[ppar][dt], racc[pj][dt]);
      }
    }
    // epilogue: consume t = 17 (pj = 2, ppar = 1, buffer 1)
    {
      const unsigned char* Pp = Pbase + 1024;
      uint2 r0 = *(const uint2*)(Pp + rbase);
      uint2 r1 = *(const uint2*)(Pp + rbase + 128);
      uint4 pa; pa.x = r0.x; pa.y = r0.y; pa.z = r1.x; pa.w = r1.y;
      #pragma unroll
      for (int dt = 0; dt < 4; ++dt)
        racc[2][dt] = mfma16(pa, vbA[1][dt], racc[2][dt]);
    }

    float lsum = psum;
    #pragma unroll
    for (int off = 32; off; off >>= 1) lsum += __shfl_xor(lsum, off, 64);

    float op[4] = {0.f, 0.f, 0.f, 0.f};
    #pragma unroll
    for (int jt = 0; jt < 3; ++jt)
      #pragma unroll
      for (int dt = 0; dt < 4; ++dt) {
        op[dt] = fmaf(bf16_lo(v1f[jt*4+dt].x), racc[jt][dt][0], op[dt]);
        op[dt] = fmaf(bf16_hi(v1f[jt*4+dt].x), racc[jt][dt][1], op[dt]);
        op[dt] = fmaf(bf16_lo(v1f[jt*4+dt].y), racc[jt][dt][2], op[dt]);
        op[dt] = fmaf(bf16_hi(v1f[jt*4+dt].y), racc[jt][dt][3], op[dt]);
      }
    #pragma unroll
    for (int dt = 0; dt < 4; ++dt) {
      op[dt] += __shfl_xor(op[dt], 16, 64);
      op[dt] += __shfl_xor(op[dt], 32, 64);
    }
    // per-wave partials into OWN P buffer 0 (P dead): redF [0,256), lsum @256
    if (l < 16) {
      #pragma unroll
      for (int dt = 0; dt < 4; ++dt)
        *(float*)(Pbase + ((dt*16 + l) << 2)) = op[dt];
    }
    if (l == 0) *(float*)(Pbase + 256) = lsum;
    __syncthreads();
    if (tid < 64) {
      float o = 0.f, lt = 0.f;
      #pragma unroll
      for (int ww = 0; ww < 4; ++ww) {
        o  += *(const float*)(lds + 49152 + ww*2048 + (tid << 2));
        lt += *(const float*)(lds + 49152 + ww*2048 + 256);
      }
      float v = o / lt;
      int m_tok = b*N_ + i0 + ii;
      int mt = m_tok >> 5, mloc = m_tok & 31;
      int g = tid >> 3, e = tid & 7;
      int off = ((((mt*8 + h)*8 + g)*32 + mloc) << 3) + e;
      unsigned short hs = (unsigned short)cvtpk(v, v);
      float resid = v - __uint_as_float(((unsigned int)hs) << 16);
      unsigned short lsb = (unsigned short)cvtpk(resid, resid);
      ATThi[off] = hs; ATTlo[off] = lsb;
    }
    __syncthreads();
  }
}

// ---------- Kernel 3: output projection (all prepacked, no LDS, no barriers) ----------
__global__ __launch_bounds__(256)
void out_proj_kernel(const uint4* __restrict__ AHi, const uint4* __restrict__ ALo,
                     const uint4* __restrict__ WoHi, const uint4* __restrict__ WoLo,
                     float* __restrict__ out)
{
  const int bn = blockIdx.x;   // 0..15
  const int bm = blockIdx.y;   // 0..11
  const int tid = threadIdx.x;
  const int w = tid >> 6, l = tid & 63;
  const int c = l & 15, q = l >> 4;
  const int mhalf = w & 1, nhalf = w >> 1;

  v4f acc = (v4f){0,0,0,0};

  for (int kc = 0; kc < 8; ++kc) {
    #pragma unroll
    for (int kh = 0; kh < 2; ++kh) {
      int g = kh*4 + q;
      int aidx = ((bm*8 + kc)*8 + g)*32 + mhalf*16 + c;
      uint4 ah = AHi[aidx];
      uint4 al = ALo[aidx];
      int nrow = bn*32 + nhalf*16 + c;
      int bidx = (((nrow >> 6)*8 + kc)*8 + g)*64 + (nrow & 63);
      uint4 bh = WoHi[bidx];
      uint4 bl = WoLo[bidx];
      acc = mfma16(ah, bh, acc);
      acc = mfma16(ah, bl, acc);
      acc = mfma16(al, bh, acc);
    }
  }

  #pragma unroll
  for (int r = 0; r < 4; ++r) {
    int m = bm*32 + mhalf*16 + q*4 + r;
    int n = bn*32 + nhalf*16 + c;
    out[(size_t)m*DIM_ + n] = acc[r];
  }
}

// ---------- launch ----------
extern "C" void kernel_launch(void* const* d_in, const int* in_sizes, int n_in,
                              void* d_out, int out_size, void* d_ws, size_t ws_size,
                              hipStream_t stream) {
  const float* tokens = (const float*)d_in[0];
  const float* w_qkv  = (const float*)d_in[1];
  const float* w_out  = (const float*)d_in[2];
  const float* qw     = (const float*)d_in[3];
  const float* k1w    = (const float*)d_in[4];
  const float* k2w    = (const float*)d_in[5];
  const float* v1w    = (const float*)d_in[6];
  const float* v2w    = (const float*)d_in[7];
  float* out = (float*)d_out;

  float* ws = (float*)d_ws;
  float* Q    = ws;                                  // 196608
  uint4* K1P  = (uint4*)(ws + 196608);               // 98304 f
  uint2* V1P  = (uint2*)(ws + 196608 + 98304);       // 98304 f
  uint4* K2P  = (uint4*)(ws + 196608 + 2*98304);     // 98304 f
  uint4* V2P  = (uint4*)(ws + 196608 + 3*98304);     // 98304 f
  uint4* AtkHi= (uint4*)(ws + 196608 + 4*98304);     // 98304 f
  uint4* AtkLo= (uint4*)(ws + 196608 + 5*98304);     // 98304 f
  uint4* WqHi = (uint4*)(ws + 196608 + 6*98304);     // 655360 f
  uint4* WqLo = (uint4*)(ws + 196608 + 6*98304 + 655360);
  uint4* WoHi = (uint4*)(ws + 196608 + 6*98304 + 2*655360);          // 131072 f
  uint4* WoLo = (uint4*)(ws + 196608 + 6*98304 + 2*655360 + 131072);
  unsigned short* ATThi = (unsigned short*)AtkHi;
  unsigned short* ATTlo = (unsigned short*)AtkLo;

  prepack_kernel<<<864, 256, 0, stream>>>(tokens, w_qkv, w_out,
                                          AtkHi, AtkLo, WqHi, WqLo, WoHi, WoLo);
  qkv_mfma_kernel<<<dim3(40, 12), 256, 0, stream>>>(AtkHi, AtkLo, WqHi, WqLo,
                                                    qw, k1w, k2w, v1w, v2w,
                                                    Q, K1P, V1P, K2P, V2P);
  attn_kernel<<<512, 256, 0, stream>>>(Q, K1P, V1P, K2P, V2P, ATThi, ATTlo);
  out_proj_kernel<<<dim3(16, 12), 256, 0, stream>>>((const uint4*)ATThi, (const uint4*)ATTlo,
                                                    WoHi, WoLo, out);
}

// Round 17
// 127.553 us; speedup vs baseline: 1.1609x; 1.0054x over previous
//
#include <hip/hip_runtime.h>

// R24 = R23 (verified 128.25us, attn 41.6us) + T5 s_setprio around attn's
// MFMA clusters. Guide evidence: setprio null on lockstep GEMM (m190) but
// +4-7% on attn with phase-diverse co-resident blocks (m191) — our attn has
// 2 independent blocks/CU. 4 instructions added; registers/LDS/numerics
// untouched (absmax must stay 1.22e-4 exactly).

#define B_ 2
#define N_ 192
#define DIM_ 512
#define H_ 8
#define DH_ 64
#define EPS_RMS 1.1920929e-7f
#define QSC 0.18033688011112042f   // 0.125 * log2(e)  (logits in base-2)
#define ARR_ (B_*H_*N_*DH_)        // 196608

typedef float v4f __attribute__((ext_vector_type(4)));
typedef short v8s __attribute__((ext_vector_type(8)));

// ---------- helpers ----------
__device__ __forceinline__ unsigned int cvtpk(float a, float b) {
  unsigned int d;
  asm("v_cvt_pk_bf16_f32 %0, %1, %2" : "=v"(d) : "v"(a), "v"(b));
  return d;
}
__device__ __forceinline__ float bf16_lo(unsigned int u) { return __uint_as_float(u << 16); }
__device__ __forceinline__ float bf16_hi(unsigned int u) { return __uint_as_float(u & 0xffff0000u); }

// exp2 via builtin ONLY (R4 lesson: raw inline-asm v_exp_f32 lacks the
// trans-op hazard wait -> stale VGPR -> NaN).
#if __has_builtin(__builtin_amdgcn_exp2f)
__device__ __forceinline__ float fexp2(float x) { return __builtin_amdgcn_exp2f(x); }
#else
__device__ __forceinline__ float fexp2(float x) {
  float r; asm("v_exp_f32 %0, %1\n\ts_nop 1" : "=v"(r) : "v"(x)); return r;
}
#endif

__device__ __forceinline__ v4f mfma16(uint4 a, uint4 b, v4f c) {
  union { uint4 u; v8s s; } ua, ub;
  ua.u = a; ub.u = b;
  return __builtin_amdgcn_mfma_f32_16x16x32_bf16(ua.s, ub.s, c, 0, 0, 0);
}

__device__ __forceinline__ void split8(const float* s, uint4& hi, uint4& lo) {
  float4 f0 = *(const float4*)s;
  float4 f1 = *(const float4*)(s + 4);
  hi.x = cvtpk(f0.x, f0.y); hi.y = cvtpk(f0.z, f0.w);
  hi.z = cvtpk(f1.x, f1.y); hi.w = cvtpk(f1.z, f1.w);
  lo.x = cvtpk(f0.x - bf16_lo(hi.x), f0.y - bf16_hi(hi.x));
  lo.y = cvtpk(f0.z - bf16_lo(hi.y), f0.w - bf16_hi(hi.y));
  lo.z = cvtpk(f1.x - bf16_lo(hi.z), f1.y - bf16_hi(hi.z));
  lo.w = cvtpk(f1.z - bf16_lo(hi.w), f1.w - bf16_hi(hi.w));
}

// ---------- Kernel 0: prepack tokens + w_qkv + w_out -> frag-ordered hi/lo bf16 ----------
__global__ __launch_bounds__(256)
void prepack_kernel(const float* __restrict__ tokens, const float* __restrict__ w_qkv,
                    const float* __restrict__ w_out,
                    uint4* __restrict__ AtkHi, uint4* __restrict__ AtkLo,
                    uint4* __restrict__ WqHi,  uint4* __restrict__ WqLo,
                    uint4* __restrict__ WoHi,  uint4* __restrict__ WoLo)
{
  int idx = blockIdx.x * 256 + threadIdx.x;     // < 221184
  const float* src; uint4 *dh, *dl; int o;
  if (idx < 24576) {
    int token = idx >> 6, kc = (idx >> 3) & 7, g = idx & 7;
    src = tokens + (size_t)token*DIM_ + kc*64 + g*8;
    o = (((token >> 5)*8 + kc)*8 + g)*32 + (token & 31);
    dh = AtkHi; dl = AtkLo;
  } else if (idx < 188416) {
    int t = idx - 24576;
    int row = t >> 6, kc = (t >> 3) & 7, g = t & 7;
    src = w_qkv + (size_t)row*DIM_ + kc*64 + g*8;
    o = (((row >> 6)*8 + kc)*8 + g)*64 + (row & 63);
    dh = WqHi; dl = WqLo;
  } else {
    int t = idx - 188416;
    int row = t >> 6, kc = (t >> 3) & 7, g = t & 7;
    src = w_out + (size_t)row*DIM_ + kc*64 + g*8;
    o = (((row >> 6)*8 + kc)*8 + g)*64 + (row & 63);
    dh = WoHi; dl = WoLo;
  }
  uint4 hi, lo; split8(src, hi, lo);
  dh[o] = hi; dl[o] = lo;
}

// ---------- Kernel 1: QKV GEMM (split-bf16 MFMA, barrier-free K loop) + RMSNorm ----------
__global__ __launch_bounds__(256)
void qkv_mfma_kernel(const uint4* __restrict__ AtkHi, const uint4* __restrict__ AtkLo,
                     const uint4* __restrict__ WqHi,  const uint4* __restrict__ WqLo,
                     const float* __restrict__ qw, const float* __restrict__ k1w,
                     const float* __restrict__ k2w, const float* __restrict__ v1w,
                     const float* __restrict__ v2w,
                     float* __restrict__ Q,
                     uint4* __restrict__ K1P, uint2* __restrict__ V1P,
                     uint4* __restrict__ K2P, uint4* __restrict__ V2P)
{
  const int bn = blockIdx.x;   // 0..39 (64 rows of w_qkv)
  const int bm = blockIdx.y;   // 0..11 (32 tokens)
  const int tid = threadIdx.x;
  const int w = tid >> 6, l = tid & 63;
  const int c = l & 15, q = l >> 4;
  const int mhalf = w & 1, nhalf = w >> 1;

  __shared__ float tile[32*64];     // 8KB, epilogue only
  __shared__ float red[32][2];

  v4f acc[2] = {(v4f){0,0,0,0}, (v4f){0,0,0,0}};

  for (int kc = 0; kc < 8; ++kc) {
    #pragma unroll
    for (int kh = 0; kh < 2; ++kh) {
      int g = kh*4 + q;
      int aidx = ((bm*8 + kc)*8 + g)*32 + mhalf*16 + c;
      uint4 ah = AtkHi[aidx];
      uint4 al = AtkLo[aidx];
      #pragma unroll
      for (int nt = 0; nt < 2; ++nt) {
        int bidx = ((bn*8 + kc)*8 + g)*64 + nhalf*32 + nt*16 + c;
        uint4 bh = WqHi[bidx];
        uint4 bl = WqLo[bidx];
        acc[nt] = mfma16(ah, bh, acc[nt]);
        acc[nt] = mfma16(ah, bl, acc[nt]);
        acc[nt] = mfma16(al, bh, acc[nt]);
      }
    }
  }

  // RMSNorm row sums (D layout: col = nhalf*32+nt*16+c, row = mhalf*16+q*4+r)
  float ss[4];
  #pragma unroll
  for (int r = 0; r < 4; ++r) {
    ss[r] = acc[0][r]*acc[0][r] + acc[1][r]*acc[1][r];
    #pragma unroll
    for (int off = 1; off < 16; off <<= 1) ss[r] += __shfl_xor(ss[r], off, 64);
  }
  if (c == 0) {
    #pragma unroll
    for (int r = 0; r < 4; ++r) red[mhalf*16 + q*4 + r][nhalf] = ss[r];
  }
  __syncthreads();

  // classify destination
  const float* nw; int hh; int kind;   // 0=Q 1=K1 2=K2 3=V1 4=V2
  if (bn < 8)       { nw = qw; hh = bn; kind = 0; }
  else if (bn < 24) { int g = bn - 8;  hh = g >> 1; kind = (g & 1) ? 2 : 1; nw = (g & 1) ? k2w : k1w; }
  else              { int g = bn - 24; hh = g >> 1; kind = (g & 1) ? 4 : 3; nw = (g & 1) ? v2w : v1w; }

  const int b = (bm >= 6) ? 1 : 0;
  const int bmm = bm - b*6;
  const int bh = b*8 + hh;

  float sc[4];
  #pragma unroll
  for (int r = 0; r < 4; ++r) {
    int row = mhalf*16 + q*4 + r;
    sc[r] = rsqrtf((red[row][0] + red[row][1]) * (1.0f/64.0f) + EPS_RMS);
  }

  if (kind == 0) {
    #pragma unroll
    for (int r = 0; r < 4; ++r) {
      int row = mhalf*16 + q*4 + r;
      size_t obase = (((size_t)bh)*N_ + bmm*32 + row)*DH_;
      #pragma unroll
      for (int nt = 0; nt < 2; ++nt) {
        int d = nhalf*32 + nt*16 + c;
        Q[obase + d] = acc[nt][r] * sc[r] * nw[d];
      }
    }
    return;
  }

  // normalized fp32 -> LDS tile [32 tok][64 d]
  #pragma unroll
  for (int r = 0; r < 4; ++r) {
    int row = mhalf*16 + q*4 + r;
    #pragma unroll
    for (int nt = 0; nt < 2; ++nt) {
      int d = nhalf*32 + nt*16 + c;
      tile[row*64 + d] = acc[nt][r] * sc[r] * nw[d];
    }
  }
  __syncthreads();

  if (kind == 1) {
    int jt_l = tid >> 7, ks = (tid >> 6) & 1, ll = tid & 63;
    int qq = ll >> 4, cc = ll & 15;
    const float* sp = tile + (jt_l*16 + cc)*64 + ks*32 + qq*8;
    uint4 wv;
    wv.x = cvtpk(sp[0], sp[1]); wv.y = cvtpk(sp[2], sp[3]);
    wv.z = cvtpk(sp[4], sp[5]); wv.w = cvtpk(sp[6], sp[7]);
    K1P[((bh*12 + bmm*2 + jt_l)*2 + ks)*64 + ll] = wv;
  } else if (kind == 2) {
    int ntl = tid >> 7, ks2 = (tid >> 6) & 1, ll = tid & 63;
    int tok = ntl*16 + (ll & 15);
    int d0 = ks2*32 + ((ll >> 4) << 3);
    const float* sp = tile + tok*64 + d0;
    uint4 wv;
    wv.x = cvtpk(sp[0], sp[1]); wv.y = cvtpk(sp[2], sp[3]);
    wv.z = cvtpk(sp[4], sp[5]); wv.w = cvtpk(sp[6], sp[7]);
    K2P[(size_t)bh*1536 + ((bmm*2 + ntl)*2 + ks2)*64 + ll] = wv;
  } else if (kind == 3) {
    #pragma unroll
    for (int pass = 0; pass < 2; ++pass) {
      int e = tid + 256*pass;
      int jt_l = e >> 8, dt = (e >> 6) & 3, ll = e & 63;
      int qq = ll >> 4, cc = ll & 15;
      int r0 = jt_l*16 + qq*4;
      int d = dt*16 + cc;
      uint2 wv;
      wv.x = cvtpk(tile[r0*64 + d],       tile[(r0+1)*64 + d]);
      wv.y = cvtpk(tile[(r0+2)*64 + d],   tile[(r0+3)*64 + d]);
      V1P[((bh*12 + bmm*2 + jt_l)*4 + dt)*64 + ll] = wv;
    }
  } else {
    int ntd = tid >> 6, ll = tid & 63;
    int dd = ntd*16 + (ll & 15);
    int t0 = (ll >> 4) << 3;
    uint4 wv;
    wv.x = cvtpk(tile[(t0+0)*64 + dd], tile[(t0+1)*64 + dd]);
    wv.y = cvtpk(tile[(t0+2)*64 + dd], tile[(t0+3)*64 + dd]);
    wv.z = cvtpk(tile[(t0+4)*64 + dd], tile[(t0+5)*64 + dd]);
    wv.w = cvtpk(tile[(t0+6)*64 + dd], tile[(t0+7)*64 + dd]);
    V2P[(size_t)bh*1536 + (ntd*6 + bmm)*64 + ll] = wv;
  }
}

// ---------- Kernel 2: two-simplicial attention ----------
// grid 512: bh = bid>>5, i0 = (bid&31)*6. 4 waves, wave w owns j in [48w,48w+48).
// Flattened t = ch*3+jt (18 steps), dual 1KB P buffers per wave (parity t&1),
// depth-1 software pipeline. T5: setprio(1) around S and PV MFMA clusters
// (2 independent blocks/CU = phase diversity; m191 evidence).
__global__ __launch_bounds__(256, 2)
void attn_kernel(const float* __restrict__ Qg,
                 const uint4* __restrict__ K1Pg, const uint2* __restrict__ V1Pg,
                 const uint4* __restrict__ K2P,  const uint4* __restrict__ V2P,
                 unsigned short* __restrict__ ATThi, unsigned short* __restrict__ ATTlo)
{
  __shared__ __align__(16) unsigned char lds[57344];
  uint4* K2B  = (uint4*)(lds);
  uint4* V2B  = (uint4*)(lds + 24576);

  const int tid = threadIdx.x;
  const int w = tid >> 6, l = tid & 63;
  const int c = l & 15, q = l >> 4;
  const int bid = blockIdx.x;
  const int bh = bid >> 5;
  const int sub = bid & 31;
  const int b = bh >> 3, h = bh & 7;
  const int i0 = sub * 6;
  const size_t base = (size_t)bh * (N_ * DH_);

  // flat copy of packed K2/V2 into LDS
  {
    const uint4* s2 = K2P + (size_t)bh*1536;
    const uint4* s3 = V2P + (size_t)bh*1536;
    #pragma unroll
    for (int t = 0; t < 6; ++t) K2B[tid + 256*t] = s2[tid + 256*t];
    #pragma unroll
    for (int t = 0; t < 6; ++t) V2B[tid + 256*t] = s3[tid + 256*t];
  }

  // K1 frags (bf16, prepacked): j = w*48+jt*16+c, d = ks*32+q*8+e
  uint4 k1f[6];
  #pragma unroll
  for (int jt = 0; jt < 3; ++jt)
    #pragma unroll
    for (int ks = 0; ks < 2; ++ks)
      k1f[jt*2+ks] = K1Pg[((bh*12 + w*3 + jt)*2 + ks)*64 + l];
  // V1 (bf16, prepacked D-read order)
  uint2 v1f[12];
  #pragma unroll
  for (int jt = 0; jt < 3; ++jt)
    #pragma unroll
    for (int dt = 0; dt < 4; ++dt)
      v1f[jt*4+dt] = V1Pg[((bh*12 + w*3 + jt)*4 + dt)*64 + l];

  __syncthreads();

  unsigned char* Pbase = lds + 49152 + w*2048;   // wave-private, 2 x 1KB
  const int rbase = (((q >> 1) * 64 + (q & 1) * 32 + c)) << 3;

  for (int ii = 0; ii < 6; ++ii) {
    float qv[2][8];
    #pragma unroll
    for (int ks = 0; ks < 2; ++ks) {
      const float* s = Qg + base + (size_t)(i0 + ii)*64 + ks*32 + (q << 3);
      float4 a = *(const float4*)s;
      float4 bq = *(const float4*)(s + 4);
      qv[ks][0]=a.x*QSC;  qv[ks][1]=a.y*QSC;  qv[ks][2]=a.z*QSC;  qv[ks][3]=a.w*QSC;
      qv[ks][4]=bq.x*QSC; qv[ks][5]=bq.y*QSC; qv[ks][6]=bq.z*QSC; qv[ks][7]=bq.w*QSC;
    }
    // B-frags: (K1 .* q_scaled) -> bf16
    uint4 afr[3][2];
    #pragma unroll
    for (int jt = 0; jt < 3; ++jt)
      #pragma unroll
      for (int ks = 0; ks < 2; ++ks) {
        uint4 kf = k1f[jt*2+ks];
        afr[jt][ks].x = cvtpk(bf16_lo(kf.x)*qv[ks][0], bf16_hi(kf.x)*qv[ks][1]);
        afr[jt][ks].y = cvtpk(bf16_lo(kf.y)*qv[ks][2], bf16_hi(kf.y)*qv[ks][3]);
        afr[jt][ks].z = cvtpk(bf16_lo(kf.z)*qv[ks][4], bf16_hi(kf.z)*qv[ks][5]);
        afr[jt][ks].w = cvtpk(bf16_lo(kf.w)*qv[ks][6], bf16_hi(kf.w)*qv[ks][7]);
      }

    v4f racc[3][4];
    #pragma unroll
    for (int jt = 0; jt < 3; ++jt)
      #pragma unroll
      for (int dt = 0; dt < 4; ++dt)
        racc[jt][dt] = (v4f){0.f, 0.f, 0.f, 0.f};
    float psum = 0.f;

    uint4 kbA[2][2];
    uint4 vbA[2][4];   // [ch&1][dt] — ping-pong so PV(t-1) at ch boundary sees old vb

    #pragma unroll
    for (int t = 0; t < 18; ++t) {
      const int ch = t / 3, jt = t % 3, par = ch & 1;
      // (1) issue P(t-1) read early — latency hides under S(t)
      uint2 r0, r1;
      if (t > 0) {
        const unsigned char* Pp = Pbase + (((t - 1) & 1) << 10);
        r0 = *(const uint2*)(Pp + rbase);
        r1 = *(const uint2*)(Pp + rbase + 128);
      }
      // (2) ch-boundary fragment loads
      if (jt == 0) {
        #pragma unroll
        for (int mt = 0; mt < 2; ++mt)
          #pragma unroll
          for (int ks = 0; ks < 2; ++ks)
            kbA[mt][ks] = K2B[((ch*2 + mt)*2 + ks)*64 + l];
        #pragma unroll
        for (int dt = 0; dt < 4; ++dt)
          vbA[par][dt] = V2B[(dt*6 + ch)*64 + l];
      }
      // (3) S phase — mt0/mt1 chains interleaved; T5 prio boost
      v4f z0 = (v4f){0.f, 0.f, 0.f, 0.f};
      v4f z1 = (v4f){0.f, 0.f, 0.f, 0.f};
      __builtin_amdgcn_s_setprio(1);
      z0 = mfma16(kbA[0][0], afr[jt][0], z0);
      z1 = mfma16(kbA[1][0], afr[jt][0], z1);
      z0 = mfma16(kbA[0][1], afr[jt][1], z0);
      z1 = mfma16(kbA[1][1], afr[jt][1], z1);
      __builtin_amdgcn_s_setprio(0);
      float p00 = fexp2(z0[0]), p01 = fexp2(z0[1]), p02 = fexp2(z0[2]), p03 = fexp2(z0[3]);
      float p10 = fexp2(z1[0]), p11 = fexp2(z1[1]), p12 = fexp2(z1[2]), p13 = fexp2(z1[3]);
      uint2 w0; w0.x = cvtpk(p00, p01); w0.y = cvtpk(p02, p03);
      uint2 w1; w1.x = cvtpk(p10, p11); w1.y = cvtpk(p12, p13);
      unsigned char* Pt = Pbase + ((t & 1) << 10);
      *(uint2*)(Pt + (l << 3)) = w0;          // slot l        (mt=0)
      *(uint2*)(Pt + ((64 + l) << 3)) = w1;   // slot 64+l     (mt=1)
      psum += (p00 + p01) + (p02 + p03);
      psum += (p10 + p11) + (p12 + p13);
      // (4) consume P(t-1); T5 prio boost
      if (t > 0) {
        const int pj = (t - 1) % 3, ppar = ((t - 1) / 3) & 1;
        uint4 pa; pa.x = r0.x; pa.y = r0.y; pa.z = r1.x; pa.w = r1.y;
        __builtin_amdgcn_s_setprio(1);
        #pragma unroll
        for (int dt = 0; dt < 4; ++dt)
          racc[pj][dt] = mfma16(pa, vbA[ppar][dt], racc[pj][dt]);
        __builtin_amdgcn_s_setprio(0);
      }
    }
    // epilogue: consume t = 17 (pj = 2, ppar = 1, buffer 1)
    {
      const unsigned char* Pp = Pbase + 1024;
      uint2 r0 = *(const uint2*)(Pp + rbase);
      uint2 r1 = *(const uint2*)(Pp + rbase + 128);
      uint4 pa; pa.x = r0.x; pa.y = r0.y; pa.z = r1.x; pa.w = r1.y;
      #pragma unroll
      for (int dt = 0; dt < 4; ++dt)
        racc[2][dt] = mfma16(pa, vbA[1][dt], racc[2][dt]);
    }

    float lsum = psum;
    #pragma unroll
    for (int off = 32; off; off >>= 1) lsum += __shfl_xor(lsum, off, 64);

    float op[4] = {0.f, 0.f, 0.f, 0.f};
    #pragma unroll
    for (int jt = 0; jt < 3; ++jt)
      #pragma unroll
      for (int dt = 0; dt < 4; ++dt) {
        op[dt] = fmaf(bf16_lo(v1f[jt*4+dt].x), racc[jt][dt][0], op[dt]);
        op[dt] = fmaf(bf16_hi(v1f[jt*4+dt].x), racc[jt][dt][1], op[dt]);
        op[dt] = fmaf(bf16_lo(v1f[jt*4+dt].y), racc[jt][dt][2], op[dt]);
        op[dt] = fmaf(bf16_hi(v1f[jt*4+dt].y), racc[jt][dt][3], op[dt]);
      }
    #pragma unroll
    for (int dt = 0; dt < 4; ++dt) {
      op[dt] += __shfl_xor(op[dt], 16, 64);
      op[dt] += __shfl_xor(op[dt], 32, 64);
    }
    // per-wave partials into OWN P buffer 0 (P dead): redF [0,256), lsum @256
    if (l < 16) {
      #pragma unroll
      for (int dt = 0; dt < 4; ++dt)
        *(float*)(Pbase + ((dt*16 + l) << 2)) = op[dt];
    }
    if (l == 0) *(float*)(Pbase + 256) = lsum;
    __syncthreads();
    if (tid < 64) {
      float o = 0.f, lt = 0.f;
      #pragma unroll
      for (int ww = 0; ww < 4; ++ww) {
        o  += *(const float*)(lds + 49152 + ww*2048 + (tid << 2));
        lt += *(const float*)(lds + 49152 + ww*2048 + 256);
      }
      float v = o / lt;
      int m_tok = b*N_ + i0 + ii;
      int mt = m_tok >> 5, mloc = m_tok & 31;
      int g = tid >> 3, e = tid & 7;
      int off = ((((mt*8 + h)*8 + g)*32 + mloc) << 3) + e;
      unsigned short hs = (unsigned short)cvtpk(v, v);
      float resid = v - __uint_as_float(((unsigned int)hs) << 16);
      unsigned short lsb = (unsigned short)cvtpk(resid, resid);
      ATThi[off] = hs; ATTlo[off] = lsb;
    }
    __syncthreads();
  }
}

// ---------- Kernel 3: output projection (all prepacked, no LDS, no barriers) ----------
__global__ __launch_bounds__(256)
void out_proj_kernel(const uint4* __restrict__ AHi, const uint4* __restrict__ ALo,
                     const uint4* __restrict__ WoHi, const uint4* __restrict__ WoLo,
                     float* __restrict__ out)
{
  const int bn = blockIdx.x;   // 0..15
  const int bm = blockIdx.y;   // 0..11
  const int tid = threadIdx.x;
  const int w = tid >> 6, l = tid & 63;
  const int c = l & 15, q = l >> 4;
  const int mhalf = w & 1, nhalf = w >> 1;

  v4f acc = (v4f){0,0,0,0};

  for (int kc = 0; kc < 8; ++kc) {
    #pragma unroll
    for (int kh = 0; kh < 2; ++kh) {
      int g = kh*4 + q;
      int aidx = ((bm*8 + kc)*8 + g)*32 + mhalf*16 + c;
      uint4 ah = AHi[aidx];
      uint4 al = ALo[aidx];
      int nrow = bn*32 + nhalf*16 + c;
      int bidx = (((nrow >> 6)*8 + kc)*8 + g)*64 + (nrow & 63);
      uint4 bh = WoHi[bidx];
      uint4 bl = WoLo[bidx];
      acc = mfma16(ah, bh, acc);
      acc = mfma16(ah, bl, acc);
      acc = mfma16(al, bh, acc);
    }
  }

  #pragma unroll
  for (int r = 0; r < 4; ++r) {
    int m = bm*32 + mhalf*16 + q*4 + r;
    int n = bn*32 + nhalf*16 + c;
    out[(size_t)m*DIM_ + n] = acc[r];
  }
}

// ---------- launch ----------
extern "C" void kernel_launch(void* const* d_in, const int* in_sizes, int n_in,
                              void* d_out, int out_size, void* d_ws, size_t ws_size,
                              hipStream_t stream) {
  const float* tokens = (const float*)d_in[0];
  const float* w_qkv  = (const float*)d_in[1];
  const float* w_out  = (const float*)d_in[2];
  const float* qw     = (const float*)d_in[3];
  const float* k1w    = (const float*)d_in[4];
  const float* k2w    = (const float*)d_in[5];
  const float* v1w    = (const float*)d_in[6];
  const float* v2w    = (const float*)d_in[7];
  float* out = (float*)d_out;

  float* ws = (float*)d_ws;
  float* Q    = ws;                                  // 196608
  uint4* K1P  = (uint4*)(ws + 196608);               // 98304 f
  uint2* V1P  = (uint2*)(ws + 196608 + 98304);       // 98304 f
  uint4* K2P  = (uint4*)(ws + 196608 + 2*98304);     // 98304 f
  uint4* V2P  = (uint4*)(ws + 196608 + 3*98304);     // 98304 f
  uint4* AtkHi= (uint4*)(ws + 196608 + 4*98304);     // 98304 f
  uint4* AtkLo= (uint4*)(ws + 196608 + 5*98304);     // 98304 f
  uint4* WqHi = (uint4*)(ws + 196608 + 6*98304);     // 655360 f
  uint4* WqLo = (uint4*)(ws + 196608 + 6*98304 + 655360);
  uint4* WoHi = (uint4*)(ws + 196608 + 6*98304 + 2*655360);          // 131072 f
  uint4* WoLo = (uint4*)(ws + 196608 + 6*98304 + 2*655360 + 131072);
  unsigned short* ATThi = (unsigned short*)AtkHi;
  unsigned short* ATTlo = (unsigned short*)AtkLo;

  prepack_kernel<<<864, 256, 0, stream>>>(tokens, w_qkv, w_out,
                                          AtkHi, AtkLo, WqHi, WqLo, WoHi, WoLo);
  qkv_mfma_kernel<<<dim3(40, 12), 256, 0, stream>>>(AtkHi, AtkLo, WqHi, WqLo,
                                                    qw, k1w, k2w, v1w, v2w,
                                                    Q, K1P, V1P, K2P, V2P);
  attn_kernel<<<512, 256, 0, stream>>>(Q, K1P, V1P, K2P, V2P, ATThi, ATTlo);
  out_proj_kernel<<<dim3(16, 12), 256, 0, stream>>>((const uint4*)ATThi, (const uint4*)ATTlo,
                                                    WoHi, WoLo, out);
}